// Round 1
// baseline (173.665 us; speedup 1.0000x reference)
//
#include <hip/hip_runtime.h>
#include <math.h>

#define IN_CH 32
#define K_OUT 4

// ---------------------------------------------------------------------------
// Kernel 1: z[n][k][i] = sum_j T[k][i][j] * x[n][j]
// One block = 128 threads = one (k,i) pair each; grid-stride over nodes.
// T (16 KB) staged in LDS once per block.
// ---------------------------------------------------------------------------
__global__ void precompute_z_kernel(const float* __restrict__ x,
                                    const float* __restrict__ T,
                                    float* __restrict__ z,
                                    int n_nodes) {
    __shared__ float Ts[K_OUT * IN_CH * IN_CH];
    for (int t = threadIdx.x; t < K_OUT * IN_CH * IN_CH; t += blockDim.x)
        Ts[t] = T[t];
    __syncthreads();

    const int ki = threadIdx.x;          // 0..127  ->  k = ki>>5, i = ki&31
    const float* Trow = Ts + ki * IN_CH; // T[k][i][:]

    for (int n = blockIdx.x; n < n_nodes; n += gridDim.x) {
        const float* xr = x + (size_t)n * IN_CH;
        float sum = 0.f;
#pragma unroll
        for (int j = 0; j < IN_CH; ++j)
            sum = fmaf(Trow[j], xr[j], sum);   // xr[j] broadcasts across lanes
        z[(size_t)n * (K_OUT * IN_CH) + ki] = sum;
    }
}

// ---------------------------------------------------------------------------
// Kernel 2: one thread per edge.
//   maps[e][k] = dot(x[src], z[dst] + k*32);  out = tanh(maps)
// x_src: 8 x float4 (128 B contiguous per lane), z_dst: 32 x float4 (512 B).
// Output: one float4 per lane, fully coalesced.
// ---------------------------------------------------------------------------
__global__ void edge_kernel(const float* __restrict__ x,
                            const float* __restrict__ z,
                            const int* __restrict__ src,
                            const int* __restrict__ dst,
                            float* __restrict__ out,
                            int n_edges) {
    int e = blockIdx.x * blockDim.x + threadIdx.x;
    if (e >= n_edges) return;

    const int s = src[e];
    const int d = dst[e];

    const float4* xs = (const float4*)(x + (size_t)s * IN_CH);
    float4 xv[8];
#pragma unroll
    for (int q = 0; q < 8; ++q) xv[q] = xs[q];

    const float4* zd = (const float4*)(z + (size_t)d * (K_OUT * IN_CH));

    float res[K_OUT];
#pragma unroll
    for (int k = 0; k < K_OUT; ++k) {
        float sum = 0.f;
#pragma unroll
        for (int q = 0; q < 8; ++q) {
            float4 zv = zd[k * 8 + q];
            sum = fmaf(xv[q].x, zv.x, sum);
            sum = fmaf(xv[q].y, zv.y, sum);
            sum = fmaf(xv[q].z, zv.z, sum);
            sum = fmaf(xv[q].w, zv.w, sum);
        }
        res[k] = tanhf(sum);
    }

    ((float4*)out)[e] = make_float4(res[0], res[1], res[2], res[3]);
}

// ---------------------------------------------------------------------------
// Fallback (ws too small): direct quadratic form per edge, T from L1.
// ---------------------------------------------------------------------------
__global__ void edge_direct_kernel(const float* __restrict__ x,
                                   const float* __restrict__ T,
                                   const int* __restrict__ src,
                                   const int* __restrict__ dst,
                                   float* __restrict__ out,
                                   int n_edges) {
    int e = blockIdx.x * blockDim.x + threadIdx.x;
    if (e >= n_edges) return;

    const int s = src[e];
    const int d = dst[e];

    float xs[IN_CH], xd[IN_CH];
#pragma unroll
    for (int j = 0; j < IN_CH; ++j) {
        xs[j] = x[(size_t)s * IN_CH + j];
        xd[j] = x[(size_t)d * IN_CH + j];
    }

    float res[K_OUT];
#pragma unroll
    for (int k = 0; k < K_OUT; ++k) {
        float acc = 0.f;
        for (int i = 0; i < IN_CH; ++i) {
            const float* Trow = T + ((size_t)k * IN_CH + i) * IN_CH;
            float yi = 0.f;
#pragma unroll
            for (int j = 0; j < IN_CH; ++j)
                yi = fmaf(Trow[j], xd[j], yi);
            acc = fmaf(xs[i], yi, acc);
        }
        res[k] = tanhf(acc);
    }
    ((float4*)out)[e] = make_float4(res[0], res[1], res[2], res[3]);
}

extern "C" void kernel_launch(void* const* d_in, const int* in_sizes, int n_in,
                              void* d_out, int out_size, void* d_ws, size_t ws_size,
                              hipStream_t stream) {
    const float* x  = (const float*)d_in[0];
    const int*   ei = (const int*)d_in[1];
    const float* T  = (const float*)d_in[2];
    float* out      = (float*)d_out;

    const int n_nodes = in_sizes[0] / IN_CH;
    const int n_edges = in_sizes[1] / 2;
    const int* src = ei;
    const int* dst = ei + n_edges;

    const size_t z_bytes = (size_t)n_nodes * K_OUT * IN_CH * sizeof(float);

    if (ws_size >= z_bytes) {
        float* z = (float*)d_ws;
        // Kernel 1: node-level precompute  z = T @ x  (per node, per k)
        precompute_z_kernel<<<2048, 128, 0, stream>>>(x, T, z, n_nodes);
        // Kernel 2: per-edge gather + 4 dot products + tanh
        const int threads = 256;
        const int blocks = (n_edges + threads - 1) / threads;
        edge_kernel<<<blocks, threads, 0, stream>>>(x, z, src, dst, out, n_edges);
    } else {
        const int threads = 256;
        const int blocks = (n_edges + threads - 1) / threads;
        edge_direct_kernel<<<blocks, threads, 0, stream>>>(x, T, src, dst, out, n_edges);
    }
}

// Round 2
// 155.900 us; speedup vs baseline: 1.1139x; 1.1139x over previous
//
#include <hip/hip_runtime.h>
#include <math.h>

#define IN_CH 32
#define K_OUT 4

// ---------------------------------------------------------------------------
// Kernel 1: z[n][k][i] = sum_j T[k][i][j] * x[n][j]
// One block = 128 threads = one (k,i) pair each; grid-stride over nodes.
// T (16 KB) staged in LDS once per block.
// ---------------------------------------------------------------------------
__global__ void precompute_z_kernel(const float* __restrict__ x,
                                    const float* __restrict__ T,
                                    float* __restrict__ z,
                                    int n_nodes) {
    __shared__ float Ts[K_OUT * IN_CH * IN_CH];
    for (int t = threadIdx.x; t < K_OUT * IN_CH * IN_CH; t += blockDim.x)
        Ts[t] = T[t];
    __syncthreads();

    const int ki = threadIdx.x;          // 0..127  ->  k = ki>>5, i = ki&31
    const float* Trow = Ts + ki * IN_CH; // T[k][i][:]

    for (int n = blockIdx.x; n < n_nodes; n += gridDim.x) {
        const float* xr = x + (size_t)n * IN_CH;
        float sum = 0.f;
#pragma unroll
        for (int j = 0; j < IN_CH; ++j)
            sum = fmaf(Trow[j], xr[j], sum);   // xr[j] broadcasts across lanes
        z[(size_t)n * (K_OUT * IN_CH) + ki] = sum;
    }
}

// ---------------------------------------------------------------------------
// Kernel 2: FOUR lanes per edge (quad-split for memory-level parallelism).
// Lane l of the quad owns x-chunk l (8 floats) and the matching 8-float slice
// of each of the 4 z_k rows: 10 independent float4 loads per lane, all
// issuable before any use -> ~4x more misses in flight per SIMD vs the
// one-edge-per-thread version, at low VGPR (full occupancy).
// Quad transpose-reduce (4x shfl_xor) leaves lane l holding maps[e][l];
// out[4e+l] = tanh -> perfectly coalesced 4B/lane stores.
// ---------------------------------------------------------------------------
__global__ __launch_bounds__(256)
void edge_kernel_quad(const float* __restrict__ x,
                      const float* __restrict__ z,
                      const int* __restrict__ src,
                      const int* __restrict__ dst,
                      float* __restrict__ out,
                      int n_edges) {
    const int t = blockIdx.x * blockDim.x + threadIdx.x;
    const int e = t >> 2;
    const int l = t & 3;
    if (e >= n_edges) return;

    const int s = src[e];   // 4-way redundant load, L1 broadcast
    const int d = dst[e];

    // x chunk l: bytes [32*l, 32*l+32) of the 128B row
    const float4* xs = (const float4*)(x + (size_t)s * IN_CH) + l * 2;
    // z row is 512B = [k][i]; lane chunk of z_k at float4 index k*8 + l*2
    const float4* zd = (const float4*)(z + (size_t)d * (K_OUT * IN_CH)) + l * 2;

    float4 xa = xs[0];
    float4 xb = xs[1];
    float4 z0a = zd[0],  z0b = zd[1];
    float4 z1a = zd[8],  z1b = zd[9];
    float4 z2a = zd[16], z2b = zd[17];
    float4 z3a = zd[24], z3b = zd[25];

    // partial dot products over this lane's 8 j-values, for each k
    float p0 = 0.f, p1 = 0.f, p2 = 0.f, p3 = 0.f;
    p0 = fmaf(xa.x, z0a.x, p0); p0 = fmaf(xa.y, z0a.y, p0);
    p0 = fmaf(xa.z, z0a.z, p0); p0 = fmaf(xa.w, z0a.w, p0);
    p0 = fmaf(xb.x, z0b.x, p0); p0 = fmaf(xb.y, z0b.y, p0);
    p0 = fmaf(xb.z, z0b.z, p0); p0 = fmaf(xb.w, z0b.w, p0);

    p1 = fmaf(xa.x, z1a.x, p1); p1 = fmaf(xa.y, z1a.y, p1);
    p1 = fmaf(xa.z, z1a.z, p1); p1 = fmaf(xa.w, z1a.w, p1);
    p1 = fmaf(xb.x, z1b.x, p1); p1 = fmaf(xb.y, z1b.y, p1);
    p1 = fmaf(xb.z, z1b.z, p1); p1 = fmaf(xb.w, z1b.w, p1);

    p2 = fmaf(xa.x, z2a.x, p2); p2 = fmaf(xa.y, z2a.y, p2);
    p2 = fmaf(xa.z, z2a.z, p2); p2 = fmaf(xa.w, z2a.w, p2);
    p2 = fmaf(xb.x, z2b.x, p2); p2 = fmaf(xb.y, z2b.y, p2);
    p2 = fmaf(xb.z, z2b.z, p2); p2 = fmaf(xb.w, z2b.w, p2);

    p3 = fmaf(xa.x, z3a.x, p3); p3 = fmaf(xa.y, z3a.y, p3);
    p3 = fmaf(xa.z, z3a.z, p3); p3 = fmaf(xa.w, z3a.w, p3);
    p3 = fmaf(xb.x, z3b.x, p3); p3 = fmaf(xb.y, z3b.y, p3);
    p3 = fmaf(xb.z, z3b.z, p3); p3 = fmaf(xb.w, z3b.w, p3);

    // Quad transpose-reduce: after this, lane l holds the full sum for k=l.
    // Round 1 (xor 1): combine (p0,p1) and (p2,p3) across lane pairs.
    float send01 = (l & 1) ? p0 : p1;
    float recv01 = __shfl_xor(send01, 1);
    float a01 = ((l & 1) ? p1 : p0) + recv01;   // even: sum-pair p0, odd: sum-pair p1
    float send23 = (l & 1) ? p2 : p3;
    float recv23 = __shfl_xor(send23, 1);
    float a23 = ((l & 1) ? p3 : p2) + recv23;   // even: sum-pair p2, odd: sum-pair p3
    // Round 2 (xor 2): combine pair-sums across the quad halves.
    float send = (l & 2) ? a01 : a23;
    float recv = __shfl_xor(send, 2);
    float r = ((l & 2) ? a23 : a01) + recv;     // lane l = full maps[e][l]

    out[t] = tanhf(r);
}

// ---------------------------------------------------------------------------
// Fallback (ws too small): direct quadratic form per edge.
// ---------------------------------------------------------------------------
__global__ void edge_direct_kernel(const float* __restrict__ x,
                                   const float* __restrict__ T,
                                   const int* __restrict__ src,
                                   const int* __restrict__ dst,
                                   float* __restrict__ out,
                                   int n_edges) {
    int e = blockIdx.x * blockDim.x + threadIdx.x;
    if (e >= n_edges) return;

    const int s = src[e];
    const int d = dst[e];

    float xs[IN_CH], xd[IN_CH];
#pragma unroll
    for (int j = 0; j < IN_CH; ++j) {
        xs[j] = x[(size_t)s * IN_CH + j];
        xd[j] = x[(size_t)d * IN_CH + j];
    }

    float res[K_OUT];
#pragma unroll
    for (int k = 0; k < K_OUT; ++k) {
        float acc = 0.f;
        for (int i = 0; i < IN_CH; ++i) {
            const float* Trow = T + ((size_t)k * IN_CH + i) * IN_CH;
            float yi = 0.f;
#pragma unroll
            for (int j = 0; j < IN_CH; ++j)
                yi = fmaf(Trow[j], xd[j], yi);
            acc = fmaf(xs[i], yi, acc);
        }
        res[k] = tanhf(acc);
    }
    ((float4*)out)[e] = make_float4(res[0], res[1], res[2], res[3]);
}

extern "C" void kernel_launch(void* const* d_in, const int* in_sizes, int n_in,
                              void* d_out, int out_size, void* d_ws, size_t ws_size,
                              hipStream_t stream) {
    const float* x  = (const float*)d_in[0];
    const int*   ei = (const int*)d_in[1];
    const float* T  = (const float*)d_in[2];
    float* out      = (float*)d_out;

    const int n_nodes = in_sizes[0] / IN_CH;
    const int n_edges = in_sizes[1] / 2;
    const int* src = ei;
    const int* dst = ei + n_edges;

    const size_t z_bytes = (size_t)n_nodes * K_OUT * IN_CH * sizeof(float);

    if (ws_size >= z_bytes) {
        float* z = (float*)d_ws;
        precompute_z_kernel<<<4096, 128, 0, stream>>>(x, T, z, n_nodes);

        // 4 lanes per edge
        const long long total = (long long)n_edges * 4;
        const int threads = 256;
        const int blocks = (int)((total + threads - 1) / threads);
        edge_kernel_quad<<<blocks, threads, 0, stream>>>(x, z, src, dst, out, n_edges);
    } else {
        const int threads = 256;
        const int blocks = (n_edges + threads - 1) / threads;
        edge_direct_kernel<<<blocks, threads, 0, stream>>>(x, T, src, dst, out, n_edges);
    }
}